// Round 14
// baseline (248.173 us; speedup 1.0000x reference)
//
#include <hip/hip_runtime.h>
#include <hip/hip_bf16.h>

#define BB 128
#define SS 128
#define EE 1024
#define NQ 8
#define DD 256
#define LL 4
#define MM (BB*SS)

typedef unsigned short bf16s;
typedef __attribute__((ext_vector_type(8))) short bf16x8;
typedef __attribute__((ext_vector_type(4))) float f32x4;

#define AS1 __attribute__((address_space(1)))
#define AS3 __attribute__((address_space(3)))

__device__ __forceinline__ unsigned short f2bf(float x) {
    unsigned u = __float_as_uint(x);
    u += 0x7fffu + ((u >> 16) & 1u);
    return (unsigned short)(u >> 16);
}

// pipeline helpers: counted vmcnt (T4) + raw barrier, sched fences (#18)
#define PIPE_WAIT(N) do { \
    asm volatile("s_waitcnt vmcnt(" #N ")" ::: "memory"); \
    __builtin_amdgcn_sched_barrier(0); \
    __builtin_amdgcn_s_barrier(); \
    __builtin_amdgcn_sched_barrier(0); } while (0)
#define PIPE_BAR() do { \
    __builtin_amdgcn_sched_barrier(0); \
    __builtin_amdgcn_s_barrier(); } while (0)
#define LGKM0_FENCE() do { \
    asm volatile("s_waitcnt lgkmcnt(0)" ::: "memory"); \
    __builtin_amdgcn_sched_barrier(0); } while (0)

// ---------------------------------------------------------------------------
// fp32 RxC -> bf16 CxR transpose-convert (weights)
// ---------------------------------------------------------------------------
__global__ __launch_bounds__(256) void transpose_conv_kernel(
    const float* __restrict__ in, bf16s* __restrict__ out, int R, int C)
{
    __shared__ float t[32][33];
    int bx = blockIdx.x * 32, by = blockIdx.y * 32;
    int lx = threadIdx.x & 31, ly = threadIdx.x >> 5;
#pragma unroll
    for (int i = 0; i < 32; i += 8)
        t[ly + i][lx] = in[(size_t)(by + ly + i) * C + bx + lx];
    __syncthreads();
#pragma unroll
    for (int i = 0; i < 32; i += 8)
        out[(size_t)(bx + ly + i) * R + by + lx] = f2bf(t[lx][ly + i]);
}

// ---------------------------------------------------------------------------
// fp32 -> bf16 straight convert (Wv), float4 vectorized
// ---------------------------------------------------------------------------
__global__ __launch_bounds__(256) void cvt_kernel(
    const float* __restrict__ in, bf16s* __restrict__ out)
{
    int g = blockIdx.x * 256 + threadIdx.x;      // float4 index
    f32x4 x = ((const f32x4*)in)[g];
    ushort4 o;
    o.x = f2bf(x[0]); o.y = f2bf(x[1]); o.z = f2bf(x[2]); o.w = f2bf(x[3]);
    ((ushort4*)out)[g] = o;
}

// ---------------------------------------------------------------------------
// bvo = bv@Wo + bo, two parallel stages.
// ---------------------------------------------------------------------------
__global__ __launch_bounds__(256) void bvo_part_kernel(
    const float* __restrict__ bv, const float* __restrict__ Wo,
    float* __restrict__ part)
{
    __shared__ float red[4][64];
    int lane = threadIdx.x & 63, w = threadIdx.x >> 6;
    int eb = blockIdx.x & 15, kb = blockIdx.x >> 4;
    int e = eb * 64 + lane;
    int k0 = kb * 64 + w * 16;
    float acc = 0.f;
#pragma unroll
    for (int i = 0; i < 16; i++)
        acc += bv[k0 + i] * Wo[(size_t)(k0 + i) * EE + e];
    red[w][lane] = acc;
    __syncthreads();
    if (w == 0)
        part[kb * EE + e] = red[0][lane] + red[1][lane] + red[2][lane] + red[3][lane];
}

__global__ __launch_bounds__(256) void bvo_reduce_kernel(
    const float* __restrict__ part, const float* __restrict__ bo,
    float* __restrict__ bvo)
{
    int e = blockIdx.x * 256 + threadIdx.x;
    float s = bo[e];
#pragma unroll
    for (int kb = 0; kb < 16; kb++) s += part[kb * EE + e];
    bvo[e] = s;
}

// ---------------------------------------------------------------------------
// Wi[1024][8] -> Wit[8][1024] fp32
// ---------------------------------------------------------------------------
__global__ __launch_bounds__(256) void wtrans_kernel(
    const float* __restrict__ Wi, float* __restrict__ Wit)
{
    int g = blockIdx.x * 256 + threadIdx.x;   // 0..8191
    int k = g >> 3, j = g & 7;
    Wit[j * 1024 + k] = Wi[g];
}

// ---------------------------------------------------------------------------
// encode v3: the lane->k map (k4 = t*64+lane) is row-invariant, so each
// lane's 128 W floats are hoisted into VGPRs ONCE per wave. Row loop has
// only 9 VMEM instrs (4 X loads, 4 Xb stores, 1 v store), zero table reads.
// 4 rows/wave, manual 1-row-ahead X prefetch overlaps the serial tail.
// ---------------------------------------------------------------------------
__global__ __launch_bounds__(256) void encode_kernel(
    const float* __restrict__ X, const float* __restrict__ Wit,
    const float* __restrict__ bi,
    bf16s* __restrict__ Xb, bf16s* __restrict__ v)
{
    const int lane = threadIdx.x & 63;
    const int wid  = threadIdx.x >> 6;
    const int row0 = blockIdx.x * 16 + wid * 4;

    // per-lane W slice: wreg[j][t] = Wit[j][(t*64+lane)*4 ..]
    f32x4 wreg[8][4];
#pragma unroll
    for (int j = 0; j < 8; j++)
#pragma unroll
        for (int t = 0; t < 4; t++)
            wreg[j][t] = ((const f32x4*)(Wit + j * 1024))[t * 64 + lane];

    float bis[8];
#pragma unroll
    for (int j = 0; j < 8; j++) bis[j] = bi[j];

    f32x4 xa0, xa1, xa2, xa3, xn0, xn1, xn2, xn3;
    {
        const f32x4* xr = (const f32x4*)(X + (size_t)row0 * EE);
        xa0 = xr[0 * 64 + lane]; xa1 = xr[1 * 64 + lane];
        xa2 = xr[2 * 64 + lane]; xa3 = xr[3 * 64 + lane];
    }

#pragma unroll
    for (int rr = 0; rr < 4; rr++) {
        const int row = row0 + rr;
        if (rr < 3) {
            const f32x4* xn = (const f32x4*)(X + (size_t)(row + 1) * EE);
            xn0 = xn[0 * 64 + lane]; xn1 = xn[1 * 64 + lane];
            xn2 = xn[2 * 64 + lane]; xn3 = xn[3 * 64 + lane];
        }

        ushort4* xbr4 = (ushort4*)(Xb + (size_t)row * EE);
        float acc[8];
#pragma unroll
        for (int j = 0; j < 8; j++) acc[j] = 0.f;

        f32x4 xs[4] = {xa0, xa1, xa2, xa3};
#pragma unroll
        for (int t = 0; t < 4; t++) {
            f32x4 x = xs[t];
            ushort4 xb;
            xb.x = f2bf(x[0]); xb.y = f2bf(x[1]);
            xb.z = f2bf(x[2]); xb.w = f2bf(x[3]);
            xbr4[t * 64 + lane] = xb;
#pragma unroll
            for (int j = 0; j < 8; j++) {
                f32x4 w = wreg[j][t];
                acc[j] += x[0]*w[0] + x[1]*w[1] + x[2]*w[2] + x[3]*w[3];
            }
        }

        float qin[8];
#pragma unroll
        for (int j = 0; j < 8; j++) {
            float s = acc[j];
#pragma unroll
            for (int off = 32; off >= 1; off >>= 1) s += __shfl_xor(s, off, 64);
            qin[j] = s + bis[j];
        }

        float cs[8], sn[8];
#pragma unroll
        for (int q = 0; q < 8; q++) __sincosf(0.5f * qin[q], &sn[q], &cs[q]);

        float common = 1.f;
#pragma unroll
        for (int b = 2; b < 8; b++) {
            int q = 7 - b;
            common *= ((lane >> (b - 2)) & 1) ? sn[q] : cs[q];
        }
        float a0 = common * cs[6] * cs[7];
        float a1 = common * cs[6] * sn[7];
        float a2 = common * sn[6] * cs[7];
        float a3 = common * sn[6] * sn[7];
        ushort4 vo;
        vo.x = f2bf(a0); vo.y = f2bf(a1); vo.z = f2bf(a2); vo.w = f2bf(a3);
        ((ushort4*)(v + (size_t)row * DD))[lane] = vo;

        xa0 = xn0; xa1 = xn1; xa2 = xn2; xa3 = xn3;
    }
}

// ---------------------------------------------------------------------------
// gemm256: C[M][N] = A[M][K] @ Bt[N][K]^T, bf16 out. 256x256 tile, 512 thr
// (8 waves 2Mx4N, wave tile 128x64), BK=32, 4 LDS K-slots (128 KB dynamic).
// v2: 2-phase-per-K-tile schedule (8-phase template, T3+T4+T5): per phase
// {ds_read subtile; stage half of kt+2; barrier; lgkmcnt(0); setprio(1);
// 16 MFMA; setprio(0); barrier}; vmcnt(4) once per K-tile at top.
// Slot safety: stage targets (kt+2)&3 != read slot kt&3; readers of that
// slot are >=2 K-tiles (>=8 barriers) upstream. T2 swizzle via
// pre-swizzled global source (rule #21). m fastest in work order.
// ---------------------------------------------------------------------------
__global__ __launch_bounds__(512) void gemm256_kernel(
    const bf16s* __restrict__ A, const bf16s* __restrict__ Bt,
    bf16s* __restrict__ C, int M, int N, int K, int nm, int nn)
{
    extern __shared__ bf16s lds[];
    bf16s* As = lds;               // 4 slots x 8192 el (256 rows x 32 k)
    bf16s* Bs = lds + 4 * 8192;    // 4 slots x 8192 el

    const int tid  = threadIdx.x;
    const int lane = tid & 63;
    const int wid  = tid >> 6;
    const int quad = lane >> 4, lr = lane & 15;
    const int wr = wid >> 2, wc = wid & 3;   // 2x4 wave grid

    const int nwg = gridDim.x;
    const int q = nwg >> 3, r = nwg & 7;
    const int xcd = blockIdx.x & 7, idx = blockIdx.x >> 3;
    const int w = (xcd < r ? xcd * (q + 1) : r * (q + 1) + (xcd - r) * q) + idx;
    const int m_t = w % nm, n_t = w / nm;    // m fastest (B-panel L2 reuse)
    const int m0 = m_t * 256, n0 = n_t * 256;

    f32x4 acc[8][4];
#pragma unroll
    for (int i = 0; i < 8; i++)
#pragma unroll
        for (int j = 0; j < 4; j++) acc[i][j] = (f32x4){0.f, 0.f, 0.f, 0.f};

    auto stageA = [&](int slot, int kt) {
#pragma unroll
        for (int l = 0; l < 2; l++) {
            int ch = l * 512 + tid;                       // 16B chunk id
            int row = ch >> 2;
            int kc = ((ch & 3) ^ (row & 3)) * 8;          // inverse-swizzled src
            __builtin_amdgcn_global_load_lds(
                (AS1 const void*)(A + (size_t)(m0 + row) * K + kt * 32 + kc),
                (AS3 void*)(As + slot * 8192 + ch * 8), 16, 0, 0);
        }
    };
    auto stageB = [&](int slot, int kt) {
#pragma unroll
        for (int l = 0; l < 2; l++) {
            int ch = l * 512 + tid;
            int row = ch >> 2;
            int kc = ((ch & 3) ^ (row & 3)) * 8;
            __builtin_amdgcn_global_load_lds(
                (AS1 const void*)(Bt + (size_t)(n0 + row) * K + kt * 32 + kc),
                (AS3 void*)(Bs + slot * 8192 + ch * 8), 16, 0, 0);
        }
    };

    const int NT = K >> 5;   // 32
    stageA(0, 0); stageB(0, 0);
    stageA(1, 1); stageB(1, 1);

    for (int kt = 0; kt < NT; kt++) {
        // top: ensure tile kt landed in all waves (vmcnt own + barrier)
        if (kt + 1 < NT) PIPE_WAIT(4);
        else             PIPE_WAIT(0);

        const int slot = kt & 3;
        const bf16s* Asl = As + slot * 8192;
        const bf16s* Bsl = Bs + slot * 8192;

        bf16x8 af[8], bfr[4];
        // ---- Phase A: read af[0..3] + bfr[0..3], stage A-half of kt+2 ----
#pragma unroll
        for (int i = 0; i < 4; i++) {
            int rowl = wr * 128 + i * 16 + lr;
            af[i] = *(const bf16x8*)(Asl + rowl * 32 + ((quad ^ (rowl & 3)) * 8));
        }
#pragma unroll
        for (int j = 0; j < 4; j++) {
            int rowl = wc * 64 + j * 16 + lr;
            bfr[j] = *(const bf16x8*)(Bsl + rowl * 32 + ((quad ^ (rowl & 3)) * 8));
        }
        if (kt + 2 < NT) stageA((kt + 2) & 3, kt + 2);
        PIPE_BAR();
        LGKM0_FENCE();
        __builtin_amdgcn_s_setprio(1);
#pragma unroll
        for (int i = 0; i < 4; i++)
#pragma unroll
            for (int j = 0; j < 4; j++)
                acc[i][j] = __builtin_amdgcn_mfma_f32_16x16x32_bf16(
                    af[i], bfr[j], acc[i][j], 0, 0, 0);
        __builtin_amdgcn_s_setprio(0);
        PIPE_BAR();

        // ---- Phase B: read af[4..7], stage B-half of kt+2 ----
#pragma unroll
        for (int i = 4; i < 8; i++) {
            int rowl = wr * 128 + i * 16 + lr;
            af[i] = *(const bf16x8*)(Asl + rowl * 32 + ((quad ^ (rowl & 3)) * 8));
        }
        if (kt + 2 < NT) stageB((kt + 2) & 3, kt + 2);
        PIPE_BAR();
        LGKM0_FENCE();
        __builtin_amdgcn_s_setprio(1);
#pragma unroll
        for (int i = 4; i < 8; i++)
#pragma unroll
            for (int j = 0; j < 4; j++)
                acc[i][j] = __builtin_amdgcn_mfma_f32_16x16x32_bf16(
                    af[i], bfr[j], acc[i][j], 0, 0, 0);
        __builtin_amdgcn_s_setprio(0);
        // no trailing barrier: next iteration's top PIPE_WAIT provides it
    }

#pragma unroll
    for (int i = 0; i < 8; i++) {
        int row0 = m0 + wr * 128 + i * 16 + quad * 4;
#pragma unroll
        for (int j = 0; j < 4; j++) {
            int col = n0 + wc * 64 + j * 16 + lr;
#pragma unroll
            for (int rr = 0; rr < 4; rr++)
                C[(size_t)(row0 + rr) * N + col] = f2bf(acc[i][j][rr]);
        }
    }
}

// ---------------------------------------------------------------------------
// MFMA bf16 GEMM: depth-2 (3-buffer) pipeline; bijective XCD chunking.
// Work order: w = (z * nm + m) * nn + n.  B row-stride = ldB.
// ---------------------------------------------------------------------------
template<bool OUT_BF16>
__global__ __launch_bounds__(256) void mfma_gemm(
    const bf16s* __restrict__ A, const bf16s* __restrict__ Bt,
    const float* __restrict__ bias, void* __restrict__ Cv,
    int M, int N, int K, int ldB, int nm, int nn,
    long long sA, long long sB, long long sC)
{
    __shared__ bf16s As[3][128 * 32];
    __shared__ bf16s Bs[3][128 * 32];

    const int tid  = threadIdx.x;
    const int wave = tid >> 6, lane = tid & 63;
    const int quad = lane >> 4, lr = lane & 15;
    const int wm = (wave >> 1) * 64, wn = (wave & 1) * 64;

    const int nwg = gridDim.x;
    const int q = nwg >> 3, r = nwg & 7;
    const int xcd = blockIdx.x & 7, idx = blockIdx.x >> 3;
    const int w = (xcd < r ? xcd * (q + 1) : r * (q + 1) + (xcd - r) * q) + idx;
    const int n_t = w % nn;
    const int m_t = (w / nn) % nm;
    const int z   = w / (nn * nm);
    const int m0 = m_t * 128, n0 = n_t * 128;

    A  += (size_t)z * sA;
    Bt += (size_t)z * sB;

    f32x4 acc[4][4];
#pragma unroll
    for (int i = 0; i < 4; i++)
#pragma unroll
        for (int j = 0; j < 4; j++) acc[i][j] = (f32x4){0.f, 0.f, 0.f, 0.f};

    auto stage = [&](int buf, int kt) {
#pragma unroll
        for (int j = 0; j < 2; j++) {
            int ch = j * 256 + tid;
            int row = ch >> 2, kc = (ch & 3) * 8;
            __builtin_amdgcn_global_load_lds(
                (AS1 const void*)(A + (size_t)(m0 + row) * K + kt + kc),
                (AS3 void*)(As[buf] + (size_t)(j * 256 + wave * 64) * 8), 16, 0, 0);
            __builtin_amdgcn_global_load_lds(
                (AS1 const void*)(Bt + (size_t)(n0 + row) * ldB + kt + kc),
                (AS3 void*)(Bs[buf] + (size_t)(j * 256 + wave * 64) * 8), 16, 0, 0);
        }
    };
    auto compute = [&](int buf) {
        bf16x8 af[4], bfr[4];
#pragma unroll
        for (int i = 0; i < 4; i++)
            af[i] = *(const bf16x8*)(As[buf] + (wm + i * 16 + lr) * 32 + quad * 8);
#pragma unroll
        for (int j = 0; j < 4; j++)
            bfr[j] = *(const bf16x8*)(Bs[buf] + (wn + j * 16 + lr) * 32 + quad * 8);
#pragma unroll
        for (int i = 0; i < 4; i++)
#pragma unroll
            for (int j = 0; j < 4; j++)
                acc[i][j] = __builtin_amdgcn_mfma_f32_16x16x32_bf16(
                    af[i], bfr[j], acc[i][j], 0, 0, 0);
    };

    const int nt = K >> 5;
    stage(0, 0);
    stage(1, 1 << 5);
    int cur = 0, nxt = 2;
    for (int t = 0; t < nt; t++) {
        if (t + 2 < nt) { stage(nxt, (t + 2) << 5); PIPE_WAIT(8); }
        else if (t + 1 < nt) PIPE_WAIT(4);
        else PIPE_WAIT(0);
        compute(cur);
        PIPE_BAR();
        cur = (cur == 2) ? 0 : cur + 1;
        nxt = (nxt == 2) ? 0 : nxt + 1;
    }

    float* Cf = (float*)Cv + (size_t)z * sC;
    bf16s* Cb = (bf16s*)Cv + (size_t)z * sC;
#pragma unroll
    for (int i = 0; i < 4; i++) {
        int row0 = m0 + wm + i * 16 + quad * 4;
#pragma unroll
        for (int j = 0; j < 4; j++) {
            int col = n0 + wn + j * 16 + lr;
            float bb = bias ? bias[col] : 0.f;
#pragma unroll
            for (int r = 0; r < 4; r++) {
                float v = acc[i][j][r] + bb;
                if (OUT_BF16) Cb[(size_t)(row0 + r) * N + col] = f2bf(v);
                else          Cf[(size_t)(row0 + r) * N + col] = v;
            }
        }
    }
}

// ---------------------------------------------------------------------------
// attn: G[s,t] = v_s . v_t (real; unitary cancels). K = G^2/sqrt(8) +
// cos(phi_t-phi_s); fused softmax. Depth-2 pipeline over v (K=256).
// ---------------------------------------------------------------------------
__global__ __launch_bounds__(256) void attn_kernel(
    const bf16s* __restrict__ v, const float* __restrict__ phi,
    float* __restrict__ attn, bf16s* __restrict__ attn_bf)
{
    __shared__ bf16s Bs[3][128 * 32];

    const int tid  = threadIdx.x;
    const int wave = tid >> 6, lane = tid & 63;
    const int quad = lane >> 4, lr = lane & 15;
    const int b = blockIdx.y;
    const int s0 = blockIdx.x * 64;
    const bf16s* vb = v + (size_t)b * 128 * DD;

    f32x4 accre[8];
#pragma unroll
    for (int j = 0; j < 8; j++) accre[j] = (f32x4){0.f, 0.f, 0.f, 0.f};

    auto stage = [&](int buf, int kt) {
#pragma unroll
        for (int j = 0; j < 2; j++) {
            int ch = j * 256 + tid;
            int row = ch >> 2, kc = (ch & 3) * 8;
            __builtin_amdgcn_global_load_lds(
                (AS1 const void*)(vb + (size_t)row * DD + kt + kc),
                (AS3 void*)(Bs[buf] + (size_t)(j * 256 + wave * 64) * 8), 16, 0, 0);
        }
    };
    auto compute = [&](int buf) {
        bf16x8 afr = *(const bf16x8*)(Bs[buf] + (s0 + wave * 16 + lr) * 32 + quad * 8);
#pragma unroll
        for (int j = 0; j < 8; j++) {
            bf16x8 b1 = *(const bf16x8*)(Bs[buf] + (j * 16 + lr) * 32 + quad * 8);
            accre[j] = __builtin_amdgcn_mfma_f32_16x16x32_bf16(afr, b1, accre[j], 0, 0, 0);
        }
    };

    const int nt = DD >> 5;   // 8
    stage(0, 0);
    stage(1, 1 << 5);
    int cur = 0, nxt = 2;
    for (int t = 0; t < nt; t++) {
        if (t + 2 < nt) { stage(nxt, (t + 2) << 5); PIPE_WAIT(4); }
        else if (t + 1 < nt) PIPE_WAIT(2);
        else PIPE_WAIT(0);
        compute(cur);
        PIPE_BAR();
        cur = (cur == 2) ? 0 : cur + 1;
        nxt = (nxt == 2) ? 0 : nxt + 1;
    }

    const float isq = 0.35355339059327373f;   // 1/sqrt(8)
    float ph_r[4], ph_c[8];
#pragma unroll
    for (int r = 0; r < 4; r++) ph_r[r] = phi[s0 + wave * 16 + quad * 4 + r];
#pragma unroll
    for (int j = 0; j < 8; j++) ph_c[j] = phi[j * 16 + lr];

#pragma unroll
    for (int r = 0; r < 4; r++) {
        float vv[8];
        float mx = -1e30f;
#pragma unroll
        for (int j = 0; j < 8; j++) {
            float re = accre[j][r];
            vv[j] = re * re * isq + __cosf(ph_c[j] - ph_r[r]);
            mx = fmaxf(mx, vv[j]);
        }
#pragma unroll
        for (int off = 1; off <= 8; off <<= 1) mx = fmaxf(mx, __shfl_xor(mx, off, 64));
        float sm = 0.f;
#pragma unroll
        for (int j = 0; j < 8; j++) { vv[j] = __expf(vv[j] - mx); sm += vv[j]; }
#pragma unroll
        for (int off = 1; off <= 8; off <<= 1) sm += __shfl_xor(sm, off, 64);
        float inv = 1.f / sm;
        int srow = b * 128 + s0 + wave * 16 + quad * 4 + r;
#pragma unroll
        for (int j = 0; j < 8; j++) {
            float o = vv[j] * inv;
            attn[(size_t)srow * 128 + j * 16 + lr] = o;
            attn_bf[(size_t)srow * 128 + j * 16 + lr] = f2bf(o);
        }
    }
}

// ---------------------------------------------------------------------------
extern "C" void kernel_launch(void* const* d_in, const int* in_sizes, int n_in,
                              void* d_out, int out_size, void* d_ws, size_t ws_size,
                              hipStream_t stream) {
    const float* X     = (const float*)d_in[0];
    const float* Wi    = (const float*)d_in[1];
    const float* bi    = (const float*)d_in[2];
    const float* Wv    = (const float*)d_in[3];
    const float* bv    = (const float*)d_in[4];
    const float* Wo    = (const float*)d_in[5];
    const float* bo    = (const float*)d_in[6];
    const float* phi   = (const float*)d_in[8];

    float* y    = (float*)d_out;
    float* attn = y + (size_t)MM * EE;

    bf16s* Xb   = (bf16s*)d_ws;                      // 16384*1024
    bf16s* Vwt  = Xb  + (size_t)MM * EE;             // [1024 e][16384 g] (X@WvWo)^T
    bf16s* v    = Vwt + (size_t)MM * EE;             // 16384*256 product states
    bf16s* abf  = v   + (size_t)MM * DD;             // 128*128*128
    bf16s* Wvb  = abf + (size_t)BB * SS * SS;        // 1024*1024 bf16(Wv)
    bf16s* Wot  = Wvb + (size_t)EE * EE;             // 1024*1024 Wo^T
    bf16s* Wvot = Wot + (size_t)EE * EE;             // 1024*1024 (Wv@Wo)^T
    float* Wit  = (float*)(Wvot + (size_t)EE * EE);  // 8*1024 fp32
    float* bvo  = Wit + 8 * 1024;                    // 1024 fp32
    float* bvop = bvo + 1024;                        // 16*1024 fp32 partials

    wtrans_kernel<<<32, 256, 0, stream>>>(Wi, Wit);
    encode_kernel<<<MM / 16, 256, 0, stream>>>(X, Wit, bi, Xb, v);
    transpose_conv_kernel<<<dim3(32, 32), 256, 0, stream>>>(Wo, Wot, EE, EE);
    cvt_kernel<<<1024, 256, 0, stream>>>(Wv, Wvb);
    bvo_part_kernel<<<256, 256, 0, stream>>>(bv, Wo, bvop);
    bvo_reduce_kernel<<<4, 256, 0, stream>>>(bvop, bo, bvo);
    // Wvot[a][b] = (Wv@Wo)[b][a] :  A=Wot, Bt=Wvb  (M=N=K=1024)
    mfma_gemm<true><<<64, 256, 0, stream>>>(
        Wot, Wvb, nullptr, Wvot, EE, EE, EE, EE, /*nm*/8, /*nn*/8, 0, 0, 0);
    // attn: real Gram of v + phase term + softmax (unitary cancels)
    attn_kernel<<<dim3(2, BB), 256, 0, stream>>>(v, phi, attn, abf);
    // Vwt[e][g] = Wvot[e][:] . Xb[g][:]  — 256^2-tile 2-phase-scheduled GEMM
    gemm256_kernel<<<256, 512, 128 * 1024, stream>>>(
        Wvot, Xb, Vwt, EE, MM, EE, /*nm*/4, /*nn*/64);
    // y_b = attn_b @ Vw_b + bvo   (B from merged Vwt: ldB=16384, batch off 128)
    mfma_gemm<false><<<1024, 256, 0, stream>>>(
        abf, Vwt, bvo, y, SS, EE, SS, MM, /*nm*/1, /*nn*/8,
        (long long)SS * SS, (long long)SS, (long long)SS * EE);
}